// Round 10
// baseline (171.613 us; speedup 1.0000x reference)
//
#include <hip/hip_runtime.h>
#include <hip/hip_bf16.h>

typedef __attribute__((ext_vector_type(8))) __bf16 bf16x8;
typedef __attribute__((ext_vector_type(16))) float f32x16;
typedef __attribute__((ext_vector_type(4))) float f32x4;

#define SCALE_L2E 14.4269504088896f // 10 * log2(e)
#define LN2 0.6931471805599453f
#define NTOT 32768

#define AS_GLOBAL __attribute__((address_space(1)))
#define AS_LDS    __attribute__((address_space(3)))

__device__ inline void async_copy16(const void* g, void* l) {
    __builtin_amdgcn_global_load_lds((const AS_GLOBAL void*)g, (AS_LDS void*)l, 16, 0, 0);
}

__device__ inline float fast_exp2(float x) {
#if __has_builtin(__builtin_amdgcn_exp2f)
    return __builtin_amdgcn_exp2f(x);      // raw v_exp_f32 (arg in [-29, 0])
#else
    return exp2f(x);
#endif
}

__device__ inline float fast_ln(float x) {
#if __has_builtin(__builtin_amdgcn_logf)
    return __builtin_amdgcn_logf(x) * LN2;  // v_log_f32 = log2
#else
    return logf(x);
#endif
}

// ---------------------------------------------------------------------------
// bf16 pack helpers (RNE)
// ---------------------------------------------------------------------------
__device__ inline unsigned int f2bf(float f) {
    unsigned int u = __builtin_bit_cast(unsigned int, f);
    u += 0x7fffu + ((u >> 16) & 1u);
    return u >> 16;
}

__device__ inline uint4 pack8(f32x4 x, f32x4 y, float s) {
    uint4 r;
    r.x = f2bf(x.x * s) | (f2bf(x.y * s) << 16);
    r.y = f2bf(x.z * s) | (f2bf(x.w * s) << 16);
    r.z = f2bf(y.x * s) | (f2bf(y.y * s) << 16);
    r.w = f2bf(y.z * s) | (f2bf(y.w * s) << 16);
    return r;
}

__device__ inline float dot8(f32x4 x, f32x4 y) {
    return x.x*y.x + x.y*y.y + x.z*y.z + x.w*y.w;
}

// ---------------------------------------------------------------------------
// Kernel 1: L2-normalize -> bf16 FRAGMENT-MAJOR, XCD-ALIGNED with gemm:
// block x handles batch b = x&15 (x%8 == b&7 == gemm's XCD for batch b), so
// the dirty E lines land in the L2 that gemm reads them from (4 MB/XCD =
// exactly 2 batches). A/B are read NONTEMPORAL (evict-first) so the 128 MB
// stream does not displace the resident E working set.
// 2048 blocks: 128 blocks/batch; waves 0-1 -> 16 A-rows, waves 2-3 -> 16 B.
// E1 PRE-SCALED by 10*log2(e). Block 0 zero-inits scalars/ctr.
// ---------------------------------------------------------------------------
__global__ __launch_bounds__(256) void nrm_kernel(
        const float* __restrict__ A, const float* __restrict__ B,
        uint4* __restrict__ E1f, uint4* __restrict__ E2f,
        float* __restrict__ scalars, unsigned int* __restrict__ ctr) {
    const int tid = threadIdx.x, w = tid >> 6, l = tid & 63;
    const int q = l & 31, h = l >> 5;
    const int b = blockIdx.x & 15;         // batch -> XCD b&7 (matches gemm)
    const int j = blockIdx.x >> 4;         // 0..127 within batch
    const int t = w >> 1;                  // 0 = A->E1, 1 = B->E2
    const int rloc = j * 16 + (w & 1) * 8; // first of this wave's 8 rows

    if (blockIdx.x == 0 && tid == 0) {
        scalars[0] = 0.f; scalars[1] = 0.f; ctr[0] = 0u;
    }

    const f32x4* S4 = (const f32x4*)(t ? B : A)
                    + ((size_t)b * 2048 + rloc + h) * 64 + q * 2;
    uint4* dst = t ? E2f : E1f;
    const float preScale = t ? 1.0f : SCALE_L2E;

    f32x4 v[8];
    #pragma unroll
    for (int i = 0; i < 4; ++i) {          // all 8 loads up front (MLP), NT
        v[2*i]   = __builtin_nontemporal_load(S4 + i * 128);
        v[2*i+1] = __builtin_nontemporal_load(S4 + i * 128 + 1);
    }

    #pragma unroll
    for (int i = 0; i < 4; ++i) {
        float sa = dot8(v[2*i], v[2*i]) + dot8(v[2*i+1], v[2*i+1]);
        #pragma unroll
        for (int off = 1; off <= 16; off <<= 1)   // stays within 32-lane half
            sa += __shfl_xor(sa, off);
        const float inv = preScale / fmaxf(sqrtf(sa), 1e-12f);

        const int rl = rloc + i * 2 + h;          // batch-local row
        const size_t chunk = (size_t)b * 65536
                           + (size_t)(rl >> 5) * 1024
                           + (q >> 1) * 64 + (q & 1) * 32 + (rl & 31);
        dst[chunk] = pack8(v[2*i], v[2*i+1], inv);
    }
}

// ---------------------------------------------------------------------------
// Kernel 2: fused GEMM + exp + row/col partials + diag extraction.
// 512 blocks (2/CU), 4 waves; block 256 rows x 512 cols; wave 64 rows.
// Partials via plain stores (read by fin across the kernel boundary = free
// flush); diag via device-scope atomicAdd (coherent, no fence).
// Blocks with ct == rt>>1 own the diagonal: col_l == row_l + (rt&1)*256.
// ---------------------------------------------------------------------------
__global__ __launch_bounds__(256, 2) void gemm_kernel(
        const bf16x8* __restrict__ E1f, const uint4* __restrict__ E2f,
        float* __restrict__ colPart, float* __restrict__ rowPart,
        float* __restrict__ scalars) {
    __shared__ bf16x8 Bbuf[2][2048];   // 2 x 32 KB (64 cols each)
    __shared__ float colLDS[2048];     // 4 per-wave slices of 512

    const int tid = threadIdx.x, w = tid >> 6, l = tid & 63;
    const int b = blockIdx.x & 15;             // XCD = b&7 (L2 pinning)
    const int ct = (blockIdx.x >> 4) & 3, rt = blockIdx.x >> 6;
    const bool diagB = (ct == (rt >> 1));
    const int dOff = (rt & 1) * 256;

    for (int i = l; i < 512; i += 64) colLDS[w * 512 + i] = 0.f;

    const uint4* Bb = E2f + (size_t)b * 65536 + (size_t)ct * 16384 + l;

    auto stage = [&](int buf, int sg) {
        const uint4* src = Bb + (size_t)sg * 2048 + (w * 8) * 64;
        #pragma unroll
        for (int j = 0; j < 8; ++j)
            async_copy16(src + j * 64, &Bbuf[buf][(w * 8 + j) * 64]);
    };

    stage(0, 0);   // DMA queued first; A-loads land behind it

    // A fragments: two 32-row tiles (fragment-major, coalesced 1KB loads)
    const bf16x8* Af0 = E1f + (size_t)b * 65536 + (size_t)(rt * 8 + w * 2) * 1024 + l;
    const bf16x8* Af1 = Af0 + 1024;
    bf16x8 af0[16], af1[16];
    #pragma unroll
    for (int kt = 0; kt < 16; ++kt) { af0[kt] = Af0[kt * 64]; af1[kt] = Af1[kt * 64]; }

    float rowAcc0[16], rowAcc1[16];
    #pragma unroll
    for (int r = 0; r < 16; ++r) { rowAcc0[r] = 0.f; rowAcc1[r] = 0.f; }
    float diagAcc = 0.f;

    __syncthreads();   // stage(0) + A-frags complete

    for (int sg = 0; sg < 8; ++sg) {
        if (sg < 7) stage((sg + 1) & 1, sg + 1);

        const bf16x8* Bf = Bbuf[sg & 1];
        for (int half = 0; half < 2; ++half) {
            f32x16 acc0, acc1;
            #pragma unroll
            for (int r = 0; r < 16; ++r) {         // bias in C-init
                acc0[r] = -SCALE_L2E; acc1[r] = -SCALE_L2E;
            }

            #pragma unroll
            for (int kt = 0; kt < 16; ++kt) {
                bf16x8 bfrag = Bf[half * 1024 + kt * 64 + l];
                acc0 = __builtin_amdgcn_mfma_f32_32x32x16_bf16(af0[kt], bfrag, acc0, 0, 0, 0);
                acc1 = __builtin_amdgcn_mfma_f32_32x32x16_bf16(af1[kt], bfrag, acc1, 0, 0, 0);
            }

            const int colL = (sg * 2 + half) * 32 + (l & 31);
            float p = 0.f;
            #pragma unroll
            for (int r = 0; r < 16; ++r) {
                float e0 = fast_exp2(acc0[r]);
                float e1 = fast_exp2(acc1[r]);
                rowAcc0[r] += e0;
                rowAcc1[r] += e1;
                p += e0 + e1;
                if (diagB) {
                    const int row0 = w * 64 + (r & 3) + 8 * (r >> 2) + 4 * (l >> 5);
                    if (colL == row0 + dOff)      diagAcc += acc0[r];
                    if (colL == row0 + 32 + dOff) diagAcc += acc1[r];
                }
            }
            p += __shfl_xor(p, 32);                 // fold 16-row halves
            if (l < 32) colLDS[w * 512 + (sg * 2 + half) * 32 + l] += p;
        }
        __syncthreads();
    }

    // row sums: reduce across 32 column-lanes
    #pragma unroll
    for (int r = 0; r < 16; ++r) {
        #pragma unroll
        for (int off = 1; off <= 16; off <<= 1) {
            rowAcc0[r] += __shfl_xor(rowAcc0[r], off);
            rowAcc1[r] += __shfl_xor(rowAcc1[r], off);
        }
    }
    if ((l & 31) == 0) {
        // C/D layout: row = (r&3) + 8*(r>>2) + 4*(lane>>5); plain stores
        float* rs = rowPart + (size_t)(b * 4 + ct) * 2048 + rt * 256 + w * 64 + 4 * (l >> 5);
        #pragma unroll
        for (int r = 0; r < 16; ++r) {
            const int rl = (r & 3) + 8 * (r >> 2);
            rs[rl]      = rowAcc0[r];
            rs[rl + 32] = rowAcc1[r];
        }
    }

    // diag: wave reduce + one device atomic per qualifying block
    if (diagB) {
        #pragma unroll
        for (int off = 1; off <= 32; off <<= 1) diagAcc += __shfl_xor(diagAcc, off);
        __shared__ float dpart[4];
        if (l == 0) dpart[w] = diagAcc;
        __syncthreads();
        if (tid == 0)
            atomicAdd(&scalars[1], dpart[0] + dpart[1] + dpart[2] + dpart[3]);
    }

    __syncthreads();   // before cross-wave colLDS fold
    float* gcol = colPart + (size_t)((b * 4 + ct) * 8 + rt) * 512;
    for (int i = tid; i < 512; i += 256)
        gcol[i] = colLDS[i] + colLDS[512 + i] + colLDS[1024 + i] + colLDS[1536 + i];
}

// ---------------------------------------------------------------------------
// Kernel 3: fold partials, sum logs, last block finalizes.
// out = (logSum - 2*ln2*diagSum) / 32768   (the +20 cancels exactly)
// ---------------------------------------------------------------------------
__global__ __launch_bounds__(256) void fin_kernel(
        const float* __restrict__ colPart, const float* __restrict__ rowPart,
        float* __restrict__ scalars, unsigned int* __restrict__ ctr,
        float* __restrict__ out) {
    const int tid = threadIdx.x;
    float s = 0.f;
    #pragma unroll
    for (int k = 0; k < 2; ++k) {
        const int g = blockIdx.x * 512 + k * 256 + tid;
        const float* cp = colPart + (size_t)(((g >> 11) * 4 + ((g >> 9) & 3)) * 8) * 512 + (g & 511);
        float cs = 0.f;
        #pragma unroll
        for (int j = 0; j < 8; ++j) cs += cp[j * 512];
        const float* rp = rowPart + (size_t)(g >> 11) * 8192 + (g & 2047);
        float rsv = rp[0] + rp[2048] + rp[4096] + rp[6144];
        s += fast_ln(cs) + fast_ln(rsv);
    }
    #pragma unroll
    for (int off = 1; off <= 32; off <<= 1) s += __shfl_xor(s, off);
    __shared__ float part[4];
    __shared__ int lastF;
    if ((tid & 63) == 0) part[tid >> 6] = s;
    __syncthreads();
    if (tid == 0) {
        const float old = atomicAdd(&scalars[0], part[0] + part[1] + part[2] + part[3]);
        const unsigned dep = (unsigned)(old * 0.0f);   // order: add before ctr
        lastF = (atomicAdd(&ctr[0], 1u + dep) == 63u) ? 1 : 0;
    }
    __syncthreads();
    if (lastF && tid == 0) {
        const float logSum  = atomicAdd(&scalars[0], 0.f);
        const float diagSum = atomicAdd(&scalars[1], 0.f);
        out[0] = (logSum - 2.0f * LN2 * diagSum) / (float)NTOT;
    }
}

// ---------------------------------------------------------------------------
extern "C" void kernel_launch(void* const* d_in, const int* in_sizes, int n_in,
                              void* d_out, int out_size, void* d_ws, size_t ws_size,
                              hipStream_t stream) {
    const float* A = (const float*)d_in[0];
    const float* B = (const float*)d_in[1];

    char* w = (char*)d_ws;
    uint4* E1f = (uint4*)w;                                    // 16 MB
    uint4* E2f = (uint4*)(w + (size_t)16 * 1024 * 1024);       // 16 MB
    float* colPart = (float*)(w + (size_t)32 * 1024 * 1024);   // 262144 f (1 MB)
    float* rowPart = colPart + 262144;                         // 131072 f (0.5 MB)
    float* scalars = rowPart + 131072;                         // [logSum, diagSum]
    unsigned int* ctr = (unsigned int*)(scalars + 2);          // [finCount]

    hipLaunchKernelGGL(nrm_kernel, dim3(2048), dim3(256), 0, stream,
                       A, B, E1f, E2f, scalars, ctr);
    hipLaunchKernelGGL(gemm_kernel, dim3(512), dim3(256), 0, stream,
                       (const bf16x8*)E1f, (const uint4*)E2f, colPart, rowPart,
                       scalars);
    hipLaunchKernelGGL(fin_kernel, dim3(64), dim3(256), 0, stream,
                       colPart, rowPart, scalars, ctr, (float*)d_out);
}

// Round 11
// 163.265 us; speedup vs baseline: 1.0511x; 1.0511x over previous
//
#include <hip/hip_runtime.h>
#include <hip/hip_bf16.h>

typedef __attribute__((ext_vector_type(8))) __bf16 bf16x8;
typedef __attribute__((ext_vector_type(16))) float f32x16;
typedef __attribute__((ext_vector_type(4))) float f32x4;

#define SCALE_L2E 14.4269504088896f // 10 * log2(e)
#define LN2 0.6931471805599453f
#define NTOT 32768

#define AS_GLOBAL __attribute__((address_space(1)))
#define AS_LDS    __attribute__((address_space(3)))

__device__ inline void async_copy16(const void* g, void* l) {
    __builtin_amdgcn_global_load_lds((const AS_GLOBAL void*)g, (AS_LDS void*)l, 16, 0, 0);
}

__device__ inline float fast_exp2(float x) {
#if __has_builtin(__builtin_amdgcn_exp2f)
    return __builtin_amdgcn_exp2f(x);      // raw v_exp_f32 (arg in [-29, 0])
#else
    return exp2f(x);
#endif
}

__device__ inline float fast_ln(float x) {
#if __has_builtin(__builtin_amdgcn_logf)
    return __builtin_amdgcn_logf(x) * LN2;  // v_log_f32 = log2
#else
    return logf(x);
#endif
}

// ---------------------------------------------------------------------------
// bf16 pack helpers (RNE)
// ---------------------------------------------------------------------------
__device__ inline unsigned int f2bf(float f) {
    unsigned int u = __builtin_bit_cast(unsigned int, f);
    u += 0x7fffu + ((u >> 16) & 1u);
    return u >> 16;
}

__device__ inline uint4 pack8(f32x4 x, f32x4 y, float s) {
    uint4 r;
    r.x = f2bf(x.x * s) | (f2bf(x.y * s) << 16);
    r.y = f2bf(x.z * s) | (f2bf(x.w * s) << 16);
    r.z = f2bf(y.x * s) | (f2bf(y.y * s) << 16);
    r.w = f2bf(y.z * s) | (f2bf(y.w * s) << 16);
    return r;
}

__device__ inline float dot8(f32x4 x, f32x4 y) {
    return x.x*y.x + x.y*y.y + x.z*y.z + x.w*y.w;
}

// ---------------------------------------------------------------------------
// Kernel 1 (R6 structure): L2-normalize -> bf16 FRAGMENT-MAJOR + fp32 diag
// partials. E1 PRE-SCALED by 10*log2(e). All 16 loads up front (MLP),
// NONTEMPORAL (A/B lines don't allocate -> fewer dirty-poison L3 evictions
// in the timed window). 1024 blocks x 4 waves x 8 rows.
// ---------------------------------------------------------------------------
__global__ __launch_bounds__(256) void nrm_kernel(
        const float* __restrict__ A, const float* __restrict__ B,
        uint4* __restrict__ E1f, uint4* __restrict__ E2f,
        float* __restrict__ diagPart) {
    const int tid = threadIdx.x, w = tid >> 6, l = tid & 63;
    const int q = l & 31, h = l >> 5;
    const int wid = blockIdx.x * 4 + w;            // 0..4095, 8 rows each

    const f32x4* A4 = (const f32x4*)A + ((size_t)wid * 8 + h) * 64 + q * 2;
    const f32x4* B4 = (const f32x4*)B + ((size_t)wid * 8 + h) * 64 + q * 2;

    f32x4 a[8], bb[8];
    #pragma unroll
    for (int i = 0; i < 4; ++i) {                  // all loads up front (MLP)
        a[2*i]    = __builtin_nontemporal_load(A4 + i * 128);
        a[2*i+1]  = __builtin_nontemporal_load(A4 + i * 128 + 1);
        bb[2*i]   = __builtin_nontemporal_load(B4 + i * 128);
        bb[2*i+1] = __builtin_nontemporal_load(B4 + i * 128 + 1);
    }

    float ddAcc = 0.f;
    #pragma unroll
    for (int i = 0; i < 4; ++i) {
        float sa = dot8(a[2*i], a[2*i]) + dot8(a[2*i+1], a[2*i+1]);
        float sb = dot8(bb[2*i], bb[2*i]) + dot8(bb[2*i+1], bb[2*i+1]);
        float dd = dot8(a[2*i], bb[2*i]) + dot8(a[2*i+1], bb[2*i+1]);
        #pragma unroll
        for (int off = 1; off <= 16; off <<= 1) {  // stays within 32-lane half
            sa += __shfl_xor(sa, off);
            sb += __shfl_xor(sb, off);
            dd += __shfl_xor(dd, off);
        }
        const float ia = 1.0f / fmaxf(sqrtf(sa), 1e-12f);
        const float ib = 1.0f / fmaxf(sqrtf(sb), 1e-12f);
        if (q == 0) ddAcc += dd * ia * ib * 10.0f;

        const int n0 = wid * 8 + i * 2 + h;
        const size_t chunk = (size_t)(n0 >> 11) * 65536
                           + (size_t)((n0 & 2047) >> 5) * 1024
                           + (q >> 1) * 64 + (q & 1) * 32 + (n0 & 31);
        E1f[chunk] = pack8(a[2*i], a[2*i+1], ia * SCALE_L2E);  // pre-scaled
        E2f[chunk] = pack8(bb[2*i], bb[2*i+1], ib);
    }

    #pragma unroll
    for (int off = 1; off <= 32; off <<= 1) ddAcc += __shfl_xor(ddAcc, off);
    __shared__ float part[4];
    if (l == 0) part[w] = ddAcc;
    __syncthreads();
    if (tid == 0) diagPart[blockIdx.x] = part[0] + part[1] + part[2] + part[3];
}

// ---------------------------------------------------------------------------
// Kernel 2 (R6 structure, 47.7 us proven): fused GEMM + exp + row/col accum.
// 512 blocks (2/CU), 4 waves; block 256 rows x 512 cols; wave 64 rows.
// B staged 64-cols (32 KB) via global_load_lds, double-buffered; 8 barriers.
// XCD pinning: b = blockIdx&15 -> XCD = b&7.
// DELTA vs R6: raw v_exp_f32 epilogue, bias folded into MFMA C-init.
// ---------------------------------------------------------------------------
__global__ __launch_bounds__(256, 2) void gemm_kernel(
        const bf16x8* __restrict__ E1f, const uint4* __restrict__ E2f,
        float* __restrict__ colSum, float* __restrict__ rowSum) {
    __shared__ bf16x8 Bbuf[2][2048];   // 2 x 32 KB (64 cols each)
    __shared__ float colLDS[2048];     // 4 per-wave slices of 512

    const int tid = threadIdx.x, w = tid >> 6, l = tid & 63;
    const int b = blockIdx.x & 15;             // XCD = b&7 (L2 pinning)
    const int ct = (blockIdx.x >> 4) & 3, rt = blockIdx.x >> 6;

    for (int i = l; i < 512; i += 64) colLDS[w * 512 + i] = 0.f;

    const uint4* Bb = E2f + (size_t)b * 65536 + (size_t)ct * 16384 + l;

    auto stage = [&](int buf, int sg) {
        const uint4* src = Bb + (size_t)sg * 2048 + (w * 8) * 64;
        #pragma unroll
        for (int j = 0; j < 8; ++j)
            async_copy16(src + j * 64, &Bbuf[buf][(w * 8 + j) * 64]);
    };

    stage(0, 0);   // DMA queued first; A-loads land behind it

    // A fragments: two 32-row tiles (fragment-major, coalesced 1KB loads)
    const bf16x8* Af0 = E1f + (size_t)b * 65536 + (size_t)(rt * 8 + w * 2) * 1024 + l;
    const bf16x8* Af1 = Af0 + 1024;
    bf16x8 af0[16], af1[16];
    #pragma unroll
    for (int kt = 0; kt < 16; ++kt) { af0[kt] = Af0[kt * 64]; af1[kt] = Af1[kt * 64]; }

    float rowAcc0[16], rowAcc1[16];
    #pragma unroll
    for (int r = 0; r < 16; ++r) { rowAcc0[r] = 0.f; rowAcc1[r] = 0.f; }

    __syncthreads();   // stage(0) + A-frags complete

    for (int sg = 0; sg < 8; ++sg) {
        if (sg < 7) stage((sg + 1) & 1, sg + 1);

        const bf16x8* Bf = Bbuf[sg & 1];
        for (int half = 0; half < 2; ++half) {
            f32x16 acc0, acc1;
            #pragma unroll
            for (int r = 0; r < 16; ++r) {         // exp bias in C-init
                acc0[r] = -SCALE_L2E; acc1[r] = -SCALE_L2E;
            }

            #pragma unroll
            for (int kt = 0; kt < 16; ++kt) {
                bf16x8 bfrag = Bf[half * 1024 + kt * 64 + l];
                acc0 = __builtin_amdgcn_mfma_f32_32x32x16_bf16(af0[kt], bfrag, acc0, 0, 0, 0);
                acc1 = __builtin_amdgcn_mfma_f32_32x32x16_bf16(af1[kt], bfrag, acc1, 0, 0, 0);
            }

            float p = 0.f;
            #pragma unroll
            for (int r = 0; r < 16; ++r) {
                float e0 = fast_exp2(acc0[r]);
                float e1 = fast_exp2(acc1[r]);
                rowAcc0[r] += e0;
                rowAcc1[r] += e1;
                p += e0 + e1;
            }
            p += __shfl_xor(p, 32);                 // fold 16-row halves
            if (l < 32) colLDS[w * 512 + (sg * 2 + half) * 32 + l] += p;
        }
        __syncthreads();
    }

    // row sums: reduce across 32 column-lanes
    #pragma unroll
    for (int r = 0; r < 16; ++r) {
        #pragma unroll
        for (int off = 1; off <= 16; off <<= 1) {
            rowAcc0[r] += __shfl_xor(rowAcc0[r], off);
            rowAcc1[r] += __shfl_xor(rowAcc1[r], off);
        }
    }
    if ((l & 31) == 0) {
        // C/D layout: row = (r&3) + 8*(r>>2) + 4*(lane>>5)
        float* rs = rowSum + (size_t)b * 2048 + rt * 256 + w * 64 + 4 * (l >> 5);
        #pragma unroll
        for (int r = 0; r < 16; ++r) {
            const int rl = (r & 3) + 8 * (r >> 2);
            atomicAdd(&rs[rl], rowAcc0[r]);
            atomicAdd(&rs[rl + 32], rowAcc1[r]);
        }
    }

    __syncthreads();   // before cross-wave colLDS fold
    float* gcol = colSum + (size_t)b * 2048 + ct * 512;
    for (int i = tid; i < 512; i += 256) {
        float s = colLDS[i] + colLDS[512 + i] + colLDS[1024 + i] + colLDS[1536 + i];
        atomicAdd(&gcol[i], s);
    }
}

// ---------------------------------------------------------------------------
// Kernel 3a: sum of log over the 65536 row+col sums (colSum||rowSum buffer).
// ---------------------------------------------------------------------------
__global__ __launch_bounds__(256) void fin1_kernel(
        const float* __restrict__ red, float* __restrict__ scalars) {
    const int tid = threadIdx.x;
    float s = 0.f;
    #pragma unroll
    for (int k = 0; k < 4; ++k)
        s += fast_ln(red[blockIdx.x * 1024 + k * 256 + tid]);
    #pragma unroll
    for (int off = 1; off <= 32; off <<= 1) s += __shfl_xor(s, off);
    __shared__ float part[4];
    if ((tid & 63) == 0) part[tid >> 6] = s;
    __syncthreads();
    if (tid == 0)
        atomicAdd(&scalars[0], part[0] + part[1] + part[2] + part[3]);
}

// ---------------------------------------------------------------------------
// Kernel 3b: reduce diagPart + finalize.
// out = (sum_logs - 2*diag)/32768 + 20   (fixed-max 10 per lse x 2 dirs)
// ---------------------------------------------------------------------------
__global__ __launch_bounds__(256) void fin2_kernel(
        const float* __restrict__ diagPart, const float* __restrict__ scalars,
        float* __restrict__ out) {
    const int tid = threadIdx.x;
    float d = 0.f;
    for (int i = tid; i < 1024; i += 256) d += diagPart[i];
    #pragma unroll
    for (int off = 1; off <= 32; off <<= 1) d += __shfl_xor(d, off);
    __shared__ float part[4];
    if ((tid & 63) == 0) part[tid >> 6] = d;
    __syncthreads();
    if (tid == 0) {
        const float diag = part[0] + part[1] + part[2] + part[3];
        out[0] = (scalars[0] - 2.0f * diag) / (float)NTOT + 20.0f;
    }
}

// ---------------------------------------------------------------------------
extern "C" void kernel_launch(void* const* d_in, const int* in_sizes, int n_in,
                              void* d_out, int out_size, void* d_ws, size_t ws_size,
                              hipStream_t stream) {
    const float* A = (const float*)d_in[0];
    const float* B = (const float*)d_in[1];

    char* w = (char*)d_ws;
    uint4* E1f = (uint4*)w;                                    // 16 MB
    uint4* E2f = (uint4*)(w + (size_t)16 * 1024 * 1024);       // 16 MB
    float* colSum = (float*)(w + (size_t)32 * 1024 * 1024);    // 32768 f
    float* rowSum = colSum + NTOT;                             // 32768 f
    float* scalars = rowSum + NTOT;                            // [logSum, pad]
    float* diagPart = scalars + 2;                             // 1024 f

    hipMemsetAsync(colSum, 0, (size_t)(2 * NTOT + 2) * 4, stream);

    hipLaunchKernelGGL(nrm_kernel, dim3(1024), dim3(256), 0, stream,
                       A, B, E1f, E2f, diagPart);
    hipLaunchKernelGGL(gemm_kernel, dim3(512), dim3(256), 0, stream,
                       (const bf16x8*)E1f, (const uint4*)E2f, colSum, rowSum);
    hipLaunchKernelGGL(fin1_kernel, dim3(64), dim3(256), 0, stream,
                       colSum, scalars);
    hipLaunchKernelGGL(fin2_kernel, dim3(1), dim3(256), 0, stream,
                       diagPart, scalars, (float*)d_out);
}